// Round 9
// baseline (656.598 us; speedup 1.0000x reference)
//
#include <hip/hip_runtime.h>
#include <math.h>

// Problem constants
#define B_N 2
#define S_N 2048
#define DM  512
#define H_N 8
#define DH  64
#define NC  32     // number of chunks = S/64
#define CH  64     // chunk length
#define NBLK 512   // grid size; 2 blocks/CU * 256 CU = exactly co-resident
#define READY_MAGIC 0x13572468u

typedef __bf16 bf16x8 __attribute__((ext_vector_type(8)));
typedef float  f32x4  __attribute__((ext_vector_type(4)));

__device__ __forceinline__ unsigned short f2bf(float f) {
    unsigned int u = __float_as_uint(f);
    u += 0x7FFFu + ((u >> 16) & 1u);          // round-to-nearest-even
    return (unsigned short)(u >> 16);
}

__device__ __forceinline__ void gload16(const void* g, void* l) {
    __builtin_amdgcn_global_load_lds(
        (const __attribute__((address_space(1))) unsigned int*)g,
        (__attribute__((address_space(3))) unsigned int*)l, 16, 0, 0);
}

// Software grid barrier: single-use counter per call site.
// All threads fence (publishes this thread's prior global writes, device
// scope -> L2 writeback on gfx95x), block arrives via device-scope
// fetch_add, leader spins on acquire load, everyone fences again
// (invalidates stale lines) before proceeding.
__device__ __forceinline__ void gridbar(unsigned* cnt) {
    __threadfence();
    __syncthreads();
    if (threadIdx.x == 0) {
        __hip_atomic_fetch_add(cnt, 1u, __ATOMIC_ACQ_REL, __HIP_MEMORY_SCOPE_AGENT);
        while (__hip_atomic_load(cnt, __ATOMIC_ACQUIRE, __HIP_MEMORY_SCOPE_AGENT) < NBLK) {
            __builtin_amdgcn_s_sleep(8);
        }
    }
    __syncthreads();
    __threadfence();
}

// ---------------------------------------------------------------------------
// One mega-kernel: 5 phases separated by software grid barriers.
// ---------------------------------------------------------------------------
__global__ __launch_bounds__(256, 2) void mega(
    const float* __restrict__ x,
    const float* __restrict__ Wqk, const float* __restrict__ bqk,
    const float* __restrict__ Wv,  const float* __restrict__ bv,
    const float* __restrict__ Wo,  const float* __restrict__ bo,
    float* __restrict__ out,
    unsigned short* __restrict__ xb,  unsigned short* __restrict__ Wqkb,
    unsigned short* __restrict__ Wvb, unsigned short* __restrict__ Wob,
    unsigned short* __restrict__ qb,  unsigned short* __restrict__ kb_,
    unsigned short* __restrict__ vtb, float* __restrict__ Asum,
    float* __restrict__ zsum, unsigned short* __restrict__ Sptb,
    unsigned short* __restrict__ ctxb, unsigned* __restrict__ bar)
{
    __shared__ union {
        struct {
            unsigned short Alds[2 * 64 * 32];
            unsigned short Blds[2 * 128 * 32];
            unsigned short ktT[64 * 72];
            unsigned short vtT[64 * 72];
        } p1;
        struct {
            unsigned short P[64 * 72];
            float nupart[64][4];
        } p3;
        struct {
            unsigned short Alds[2 * 64 * 32];
            unsigned short Blds[2 * 64 * 32];
        } p4;
    } sm;

    const int tid = threadIdx.x;
    const int bid = blockIdx.x;
    const int w = tid >> 6, l = tid & 63;
    const int lane15 = l & 15, quad = l >> 4;

    // ---- barrier init (ws arrives poisoned 0xAA every launch) ----
    if (bid == 0) {
        if (tid < 8)
            __hip_atomic_store(&bar[tid], 0u, __ATOMIC_RELAXED, __HIP_MEMORY_SCOPE_AGENT);
        __syncthreads();   // drains the stores (vmcnt) before flag release
        if (tid == 0)
            __hip_atomic_store(&bar[8], READY_MAGIC, __ATOMIC_RELEASE, __HIP_MEMORY_SCOPE_AGENT);
    } else {
        if (tid == 0) {
            while (__hip_atomic_load(&bar[8], __ATOMIC_ACQUIRE, __HIP_MEMORY_SCOPE_AGENT) != READY_MAGIC) {
                __builtin_amdgcn_s_sleep(2);
            }
        }
        __syncthreads();
    }

    // ============================ Phase 0: convert =========================
    for (int gid = bid * 256 + tid; gid < 786432; gid += NBLK * 256) {
        const float* src; unsigned short* dst; int off;
        if (gid < 524288)      { src = x;   dst = xb;   off = gid; }
        else if (gid < 655360) { src = Wqk; dst = Wqkb; off = gid - 524288; }
        else if (gid < 720896) { src = Wv;  dst = Wvb;  off = gid - 655360; }
        else                   { src = Wo;  dst = Wob;  off = gid - 720896; }
        float4 v = ((const float4*)src)[off];
        ushort4 r; r.x = f2bf(v.x); r.y = f2bf(v.y); r.z = f2bf(v.z); r.w = f2bf(v.w);
        ((ushort4*)dst)[off] = r;
    }
    gridbar(&bar[0]);

    // ==================== Phase 1: projection + chunk states ===============
    // 768 tiles (12 bx x 64 m-groups) grid-strided over 512 blocks.  BK=64.
    for (int tile = bid; tile < 768; tile += NBLK) {
        const int bx = tile % 12;
        const int m0 = (tile / 12) * 64;
        const int isq = (bx < 4);
        const int h = isq ? 0 : (bx - 4);
        const int wm = w >> 1, wn = w & 1;
        const int srow = w * 16 + (l >> 2);
        const int skof = (l & 3) << 3;

        f32x4 acc[2][4];
        #pragma unroll
        for (int i = 0; i < 2; i++)
            #pragma unroll
            for (int j = 0; j < 4; j++) acc[i][j] = (f32x4){0.f, 0.f, 0.f, 0.f};

        for (int k0 = 0; k0 < DM; k0 += 64) {
            __syncthreads();
            gload16(&xb[(size_t)(m0 + srow) * DM + k0 + skof],      (char*)sm.p1.Alds + w * 1024);
            gload16(&xb[(size_t)(m0 + srow) * DM + k0 + 32 + skof], (char*)sm.p1.Alds + 4096 + w * 1024);
            if (isq) {
                gload16(&Wqkb[(size_t)(bx * 128 + srow) * DM + k0 + skof],           (char*)sm.p1.Blds + w * 1024);
                gload16(&Wqkb[(size_t)(bx * 128 + 64 + srow) * DM + k0 + skof],      (char*)sm.p1.Blds + 4096 + w * 1024);
                gload16(&Wqkb[(size_t)(bx * 128 + srow) * DM + k0 + 32 + skof],      (char*)sm.p1.Blds + 8192 + w * 1024);
                gload16(&Wqkb[(size_t)(bx * 128 + 64 + srow) * DM + k0 + 32 + skof], (char*)sm.p1.Blds + 12288 + w * 1024);
            } else {
                gload16(&Wqkb[(size_t)(512 + h * 64 + srow) * DM + k0 + skof],       (char*)sm.p1.Blds + w * 1024);
                gload16(&Wvb[(size_t)(h * 64 + srow) * DM + k0 + skof],              (char*)sm.p1.Blds + 4096 + w * 1024);
                gload16(&Wqkb[(size_t)(512 + h * 64 + srow) * DM + k0 + 32 + skof],  (char*)sm.p1.Blds + 8192 + w * 1024);
                gload16(&Wvb[(size_t)(h * 64 + srow) * DM + k0 + 32 + skof],         (char*)sm.p1.Blds + 12288 + w * 1024);
            }
            __syncthreads();

            #pragma unroll
            for (int s = 0; s < 2; s++) {
                bf16x8 af[2], bfr[4];
                #pragma unroll
                for (int i = 0; i < 2; i++)
                    af[i] = *(bf16x8*)&sm.p1.Alds[s * 2048 + (wm * 32 + i * 16 + lane15) * 32 + quad * 8];
                #pragma unroll
                for (int j = 0; j < 4; j++)
                    bfr[j] = *(bf16x8*)&sm.p1.Blds[s * 4096 + (wn * 64 + j * 16 + lane15) * 32 + quad * 8];
                #pragma unroll
                for (int i = 0; i < 2; i++)
                    #pragma unroll
                    for (int j = 0; j < 4; j++)
                        acc[i][j] = __builtin_amdgcn_mfma_f32_16x16x32_bf16(af[i], bfr[j], acc[i][j], 0, 0, 0);
            }
        }

        const int bbu = m0 >> 11;
        const int t0  = m0 & (S_N - 1);
        const int c0  = t0 >> 6;

        if (isq) {
            #pragma unroll
            for (int i = 0; i < 2; i++) {
                #pragma unroll
                for (int rg = 0; rg < 4; rg++) {
                    int m = m0 + wm * 32 + i * 16 + quad * 4 + rg;
                    int bb = m >> 11, t = m & (S_N - 1);
                    #pragma unroll
                    for (int j = 0; j < 4; j++) {
                        int n = bx * 128 + wn * 64 + j * 16 + lane15;   // 0..511
                        float val = acc[i][j][rg] + bqk[n];
                        val = (val > 0.f) ? (val + 1.f) : __expf(val);
                        qb[(((size_t)bb * H_N + (n >> 6)) * S_N + t) * DH + (n & 63)] = f2bf(val);
                    }
                }
            }
        } else {
            #pragma unroll
            for (int i = 0; i < 2; i++) {
                #pragma unroll
                for (int rg = 0; rg < 4; rg++) {
                    int tl = wm * 32 + i * 16 + quad * 4 + rg;   // local row 0..63
                    int t  = t0 + tl;
                    #pragma unroll
                    for (int j = 0; j < 4; j++) {
                        int col = j * 16 + lane15;               // 0..63 within half
                        if (wn == 0) {
                            float val = acc[i][j][rg] + bqk[512 + h * 64 + col];
                            val = (val > 0.f) ? (val + 1.f) : __expf(val);
                            unsigned short us = f2bf(val);
                            kb_[(((size_t)bbu * H_N + h) * S_N + t) * DH + col] = us;
                            sm.p1.ktT[col * 72 + tl] = us;
                        } else {
                            float val = acc[i][j][rg] + bv[h * 64 + col];
                            sm.p1.vtT[col * 72 + tl] = f2bf(val);
                        }
                    }
                }
            }
            __syncthreads();

            // coalesced copy vT -> vtb global [bh][d][t]
            {
                size_t vbase = (((size_t)bbu * H_N + h) * DH) * S_N + t0;
                #pragma unroll
                for (int it = 0; it < 2; it++) {
                    int idx = it * 2048 + tid * 8;
                    int d = idx >> 6, tt = idx & 63;
                    *(bf16x8*)&vtb[vbase + (size_t)d * S_N + tt] = *(bf16x8*)&sm.p1.vtT[d * 72 + tt];
                }
            }

            // St via MFMA; wave w owns d2 rows 16w..16w+15
            {
                int blk = ((bbu * H_N + h) * NC) + c0;
                bf16x8 va[2];
                #pragma unroll
                for (int s = 0; s < 2; s++)
                    va[s] = *(bf16x8*)&sm.p1.vtT[(w * 16 + lane15) * 72 + s * 32 + quad * 8];
                f32x4 sacc[4];
                #pragma unroll
                for (int j = 0; j < 4; j++) sacc[j] = (f32x4){0.f, 0.f, 0.f, 0.f};
                #pragma unroll
                for (int j = 0; j < 4; j++)
                    #pragma unroll
                    for (int s = 0; s < 2; s++) {
                        bf16x8 kB = *(bf16x8*)&sm.p1.ktT[(j * 16 + lane15) * 72 + s * 32 + quad * 8];
                        sacc[j] = __builtin_amdgcn_mfma_f32_16x16x32_bf16(va[s], kB, sacc[j], 0, 0, 0);
                    }
                #pragma unroll
                for (int j = 0; j < 4; j++)
                    #pragma unroll
                    for (int rg = 0; rg < 4; rg++)
                        Asum[(size_t)blk * 4096 + (w * 16 + quad * 4 + rg) * 64 + j * 16 + lane15] = sacc[j][rg];
            }

            // z: threads 0..63, one d1 each
            if (tid < 64) {
                float z = 0.f;
                #pragma unroll
                for (int p = 0; p < 8; p++) {
                    bf16x8 kk = *(bf16x8*)&sm.p1.ktT[tid * 72 + p * 8];
                    #pragma unroll
                    for (int e = 0; e < 8; e++) z += (float)kk[e];
                }
                zsum[(size_t)((bbu * H_N + h) * NC + c0) * 64 + tid] = z;
            }
            __syncthreads();   // protect ktT/vtT before next tile's staging
        }
    }
    gridbar(&bar[1]);

    // ========================= Phase 2: prefix scan ========================
    {
        const int gid = bid * 256 + tid;
        if (gid < 66560) {
            const int bh = gid / 4160;
            const int r  = gid % 4160;
            if (r < 4096) {
                size_t base = (size_t)bh * NC * 4096 + r;
                float vals[NC];
                #pragma unroll
                for (int c = 0; c < NC; c++) vals[c] = Asum[base + (size_t)c * 4096];
                float acc = 0.f;
                #pragma unroll
                for (int c = 0; c < NC; c++) {
                    float tmp = vals[c];
                    Sptb[base + (size_t)c * 4096] = f2bf(acc);
                    acc += tmp;
                }
            } else {
                int d = r - 4096;
                size_t base = (size_t)bh * NC * 64 + d;
                float vals[NC];
                #pragma unroll
                for (int c = 0; c < NC; c++) vals[c] = zsum[base + (size_t)c * 64];
                float acc = 0.f;
                #pragma unroll
                for (int c = 0; c < NC; c++) {
                    float tmp = vals[c];
                    zsum[base + (size_t)c * 64] = acc;
                    acc += tmp;
                }
            }
        }
    }
    gridbar(&bar[2]);

    // ========================== Phase 3: attention =========================
    {
        const int blk = bid;                  // 0..511
        const int bh = blk >> 5, c = blk & 31;
        const int b = bh >> 3, h = bh & 7;

        const unsigned short* qc  = qb  + (size_t)bh * S_N * DH + c * CH * DH;  // [t][d]
        const unsigned short* kc  = kb_ + (size_t)bh * S_N * DH + c * CH * DH;  // [u][d]
        const unsigned short* vtc = vtb + (size_t)bh * DH * S_N + c * CH;       // [d2][t]
        const unsigned short* spc = Sptb + (size_t)blk * 4096;                  // [d2][d1]
        const float* zc = zsum + (size_t)blk * 64;

        bf16x8 af[2];
        #pragma unroll
        for (int s = 0; s < 2; s++)
            af[s] = *(const bf16x8*)&qc[(w * 16 + lane15) * DH + s * 32 + quad * 8];

        // scores S[t][u]
        f32x4 sacc[4];
        #pragma unroll
        for (int j = 0; j < 4; j++) sacc[j] = (f32x4){0.f, 0.f, 0.f, 0.f};
        #pragma unroll
        for (int j = 0; j < 4; j++)
            #pragma unroll
            for (int s = 0; s < 2; s++) {
                bf16x8 bk = *(const bf16x8*)&kc[(j * 16 + lane15) * DH + s * 32 + quad * 8];
                sacc[j] = __builtin_amdgcn_mfma_f32_16x16x32_bf16(af[s], bk, sacc[j], 0, 0, 0);
            }

        // causal mask + store P (bf16) to LDS
        const int r0 = w * 16 + quad * 4;
        #pragma unroll
        for (int j = 0; j < 4; j++) {
            int u = j * 16 + lane15;
            #pragma unroll
            for (int rg = 0; rg < 4; rg++) {
                int rr = r0 + rg;
                float v = (u <= rr) ? sacc[j][rg] : 0.f;
                sm.p3.P[rr * 72 + u] = f2bf(v);
            }
        }
        __syncthreads();

        // nu: thread (tl, part) sums P[tl][16*part..+15] + q.zprev strip
        const int tl = tid >> 2, part = tid & 3;
        float nup = 0.f;
        {
            bf16x8 p0 = *(const bf16x8*)&sm.p3.P[tl * 72 + part * 16];
            bf16x8 p1 = *(const bf16x8*)&sm.p3.P[tl * 72 + part * 16 + 8];
            bf16x8 q0 = *(const bf16x8*)&qc[tl * DH + part * 16];
            bf16x8 q1 = *(const bf16x8*)&qc[tl * DH + part * 16 + 8];
            #pragma unroll
            for (int i = 0; i < 8; i++) {
                nup += (float)p0[i] + (float)p1[i];
                nup += (float)q0[i] * zc[part * 16 + i];
                nup += (float)q1[i] * zc[part * 16 + 8 + i];
            }
        }
        sm.p3.nupart[tl][part] = nup;
        __syncthreads();

        // numerator: intra (P @ vt) + inter (q @ Spt), fused accumulator
        bf16x8 pa[2];
        #pragma unroll
        for (int s = 0; s < 2; s++)
            pa[s] = *(const bf16x8*)&sm.p3.P[(w * 16 + lane15) * 72 + s * 32 + quad * 8];

        f32x4 acc[4];
        #pragma unroll
        for (int j = 0; j < 4; j++) acc[j] = (f32x4){0.f, 0.f, 0.f, 0.f};
        #pragma unroll
        for (int j = 0; j < 4; j++)
            #pragma unroll
            for (int s = 0; s < 2; s++) {
                bf16x8 bv8 = *(const bf16x8*)&vtc[(size_t)(j * 16 + lane15) * S_N + s * 32 + quad * 8];
                acc[j] = __builtin_amdgcn_mfma_f32_16x16x32_bf16(pa[s], bv8, acc[j], 0, 0, 0);
                bf16x8 bs = *(const bf16x8*)&spc[(j * 16 + lane15) * 64 + s * 32 + quad * 8];
                acc[j] = __builtin_amdgcn_mfma_f32_16x16x32_bf16(af[s], bs, acc[j], 0, 0, 0);
            }

        // epilogue: divide by nu, write ctx bf16 [b*S+t][DM]
        #pragma unroll
        for (int rg = 0; rg < 4; rg++) {
            int rr = r0 + rg;
            float nu = sm.p3.nupart[rr][0] + sm.p3.nupart[rr][1] + sm.p3.nupart[rr][2] + sm.p3.nupart[rr][3];
            float inv = 1.f / nu;
            size_t obase = ((size_t)b * S_N + c * CH + rr) * DM + h * DH;
            #pragma unroll
            for (int j = 0; j < 4; j++)
                ctxb[obase + j * 16 + lane15] = f2bf(acc[j][rg] * inv);
        }
    }
    gridbar(&bar[3]);

    // ======================== Phase 4: output GEMM =========================
    {
        const int n0 = (bid & 7) * 64;
        const int m0 = (bid >> 3) * 64;
        const int wm = w >> 1, wn = w & 1;
        const int srow = w * 16 + (l >> 2);
        const int skof = (l & 3) << 3;

        f32x4 acc[2][2];
        #pragma unroll
        for (int i = 0; i < 2; i++)
            #pragma unroll
            for (int j = 0; j < 2; j++) acc[i][j] = (f32x4){0.f, 0.f, 0.f, 0.f};

        for (int k0 = 0; k0 < DM; k0 += 64) {
            __syncthreads();
            gload16(&ctxb[(size_t)(m0 + srow) * DM + k0 + skof],      (char*)sm.p4.Alds + w * 1024);
            gload16(&ctxb[(size_t)(m0 + srow) * DM + k0 + 32 + skof], (char*)sm.p4.Alds + 4096 + w * 1024);
            gload16(&Wob[(size_t)(n0 + srow) * DM + k0 + skof],       (char*)sm.p4.Blds + w * 1024);
            gload16(&Wob[(size_t)(n0 + srow) * DM + k0 + 32 + skof],  (char*)sm.p4.Blds + 4096 + w * 1024);
            __syncthreads();

            #pragma unroll
            for (int s = 0; s < 2; s++) {
                bf16x8 af2[2], bfr[2];
                #pragma unroll
                for (int i = 0; i < 2; i++)
                    af2[i] = *(bf16x8*)&sm.p4.Alds[s * 2048 + (wm * 32 + i * 16 + lane15) * 32 + quad * 8];
                #pragma unroll
                for (int j = 0; j < 2; j++)
                    bfr[j] = *(bf16x8*)&sm.p4.Blds[s * 2048 + (wn * 32 + j * 16 + lane15) * 32 + quad * 8];
                #pragma unroll
                for (int i = 0; i < 2; i++)
                    #pragma unroll
                    for (int j = 0; j < 2; j++)
                        acc[i][j] = __builtin_amdgcn_mfma_f32_16x16x32_bf16(af2[i], bfr[j], acc[i][j], 0, 0, 0);
            }
        }

        #pragma unroll
        for (int i = 0; i < 2; i++) {
            #pragma unroll
            for (int rg = 0; rg < 4; rg++) {
                int m = m0 + wm * 32 + i * 16 + quad * 4 + rg;
                #pragma unroll
                for (int j = 0; j < 2; j++) {
                    int n = n0 + wn * 32 + j * 16 + lane15;
                    out[(size_t)m * DM + n] = acc[i][j][rg] + bo[n];
                }
            }
        }
    }
}

// ---------------------------------------------------------------------------
extern "C" void kernel_launch(void* const* d_in, const int* in_sizes, int n_in,
                              void* d_out, int out_size, void* d_ws, size_t ws_size,
                              hipStream_t stream)
{
    const float* x   = (const float*)d_in[0];
    const float* Wqk = (const float*)d_in[1];
    const float* bqk = (const float*)d_in[2];
    const float* Wv  = (const float*)d_in[3];
    const float* bv  = (const float*)d_in[4];
    const float* Wo  = (const float*)d_in[5];
    const float* bo  = (const float*)d_in[6];
    float* out = (float*)d_out;

    const size_t NTOK = (size_t)B_N * S_N * DM;   // 2,097,152
    float* Asum = (float*)d_ws;                   // NTOK fp32
    float* zsum = Asum + NTOK;                    // 32768 fp32
    unsigned short* xb   = (unsigned short*)(zsum + 32768);
    unsigned short* Wqkb = xb   + NTOK;
    unsigned short* Wvb  = Wqkb + 524288;
    unsigned short* Wob  = Wvb  + 262144;
    unsigned short* qb   = Wob  + 262144;
    unsigned short* kb_  = qb   + NTOK;
    unsigned short* vtb  = kb_  + NTOK;
    unsigned short* Sptb = vtb  + NTOK;
    unsigned short* ctxb = Sptb + NTOK;
    unsigned* bar        = (unsigned*)(ctxb + NTOK);   // 16 counters

    mega<<<dim3(NBLK), dim3(256), 0, stream>>>(
        x, Wqk, bqk, Wv, bv, Wo, bo, out,
        xb, Wqkb, Wvb, Wob, qb, kb_, vtb, Asum, zsum, Sptb, ctxb, bar);
}

// Round 10
// 121.234 us; speedup vs baseline: 5.4160x; 5.4160x over previous
//
#include <hip/hip_runtime.h>
#include <math.h>

// Problem constants
#define B_N 2
#define S_N 2048
#define DM  512
#define H_N 8
#define DH  64
#define NC  32     // number of chunks = S/64
#define CH  64     // chunk length

typedef __bf16 bf16x8 __attribute__((ext_vector_type(8)));
typedef float  f32x4  __attribute__((ext_vector_type(4)));

__device__ __forceinline__ unsigned short f2bf(float f) {
    unsigned int u = __float_as_uint(f);
    u += 0x7FFFu + ((u >> 16) & 1u);          // round-to-nearest-even
    return (unsigned short)(u >> 16);
}

__device__ __forceinline__ void gload16(const void* g, void* l) {
    __builtin_amdgcn_global_load_lds(
        (const __attribute__((address_space(1))) unsigned int*)g,
        (__attribute__((address_space(3))) unsigned int*)l, 16, 0, 0);
}

// ---------------------------------------------------------------------------
// Kernel 0: fp32 -> bf16 conversion of x, Wqk, Wv, Wo.
// ---------------------------------------------------------------------------
__global__ __launch_bounds__(256) void convert_bf16(
    const float* __restrict__ x,  const float* __restrict__ wqk,
    const float* __restrict__ wv, const float* __restrict__ wo,
    unsigned short* __restrict__ xb,  unsigned short* __restrict__ wqkb,
    unsigned short* __restrict__ wvb, unsigned short* __restrict__ wob)
{
    int gid = blockIdx.x * 256 + threadIdx.x;   // 0..786431 float4 units
    const float* src; unsigned short* dst; int off;
    if (gid < 524288)      { src = x;   dst = xb;   off = gid; }
    else if (gid < 655360) { src = wqk; dst = wqkb; off = gid - 524288; }
    else if (gid < 720896) { src = wv;  dst = wvb;  off = gid - 655360; }
    else                   { src = wo;  dst = wob;  off = gid - 720896; }
    float4 v = ((const float4*)src)[off];
    ushort4 r; r.x = f2bf(v.x); r.y = f2bf(v.y); r.z = f2bf(v.z); r.w = f2bf(v.w);
    ((ushort4*)dst)[off] = r;
}

// ---------------------------------------------------------------------------
// Kernel 1: fused projection + per-chunk state sums.  64-row m-tiles, BK=64.
// grid = (12, 64):  bx<4  -> q-blocks;  bx>=4 -> kv-blocks (head h=bx-4).
// ---------------------------------------------------------------------------
__global__ __launch_bounds__(256) void gemm_qkv_fused(
    const unsigned short* __restrict__ xb,
    const unsigned short* __restrict__ Wqkb,
    const unsigned short* __restrict__ Wvb,
    const float* __restrict__ bqk, const float* __restrict__ bv,
    unsigned short* __restrict__ qb, unsigned short* __restrict__ kb_,
    unsigned short* __restrict__ vtb,
    float* __restrict__ Asum, float* __restrict__ zsum)
{
    __shared__ unsigned short Alds[2 * 64 * 32];    // [half][64][32]
    __shared__ unsigned short Blds[2 * 128 * 32];   // [half][128][32]
    __shared__ unsigned short ktT[64 * 72];
    __shared__ unsigned short vtT[64 * 72];

    const int tid = threadIdx.x;
    const int w = tid >> 6, l = tid & 63;
    const int wm = w >> 1, wn = w & 1;
    const int lane15 = l & 15, quad = l >> 4;
    const int bx = blockIdx.x;
    const int m0 = blockIdx.y * 64;    // grid.y = 64
    const int isq = (bx < 4);
    const int h = isq ? 0 : (bx - 4);

    const int srow = w * 16 + (l >> 2);   // 0..63
    const int skof = (l & 3) << 3;

    f32x4 acc[2][4];
    #pragma unroll
    for (int i = 0; i < 2; i++)
        #pragma unroll
        for (int j = 0; j < 4; j++) acc[i][j] = (f32x4){0.f, 0.f, 0.f, 0.f};

    for (int k0 = 0; k0 < DM; k0 += 64) {
        __syncthreads();
        gload16(&xb[(size_t)(m0 + srow) * DM + k0 + skof],      (char*)Alds + w * 1024);
        gload16(&xb[(size_t)(m0 + srow) * DM + k0 + 32 + skof], (char*)Alds + 4096 + w * 1024);
        if (isq) {
            gload16(&Wqkb[(size_t)(bx * 128 + srow) * DM + k0 + skof],           (char*)Blds + w * 1024);
            gload16(&Wqkb[(size_t)(bx * 128 + 64 + srow) * DM + k0 + skof],      (char*)Blds + 4096 + w * 1024);
            gload16(&Wqkb[(size_t)(bx * 128 + srow) * DM + k0 + 32 + skof],      (char*)Blds + 8192 + w * 1024);
            gload16(&Wqkb[(size_t)(bx * 128 + 64 + srow) * DM + k0 + 32 + skof], (char*)Blds + 12288 + w * 1024);
        } else {
            gload16(&Wqkb[(size_t)(512 + h * 64 + srow) * DM + k0 + skof],       (char*)Blds + w * 1024);
            gload16(&Wvb[(size_t)(h * 64 + srow) * DM + k0 + skof],              (char*)Blds + 4096 + w * 1024);
            gload16(&Wqkb[(size_t)(512 + h * 64 + srow) * DM + k0 + 32 + skof],  (char*)Blds + 8192 + w * 1024);
            gload16(&Wvb[(size_t)(h * 64 + srow) * DM + k0 + 32 + skof],         (char*)Blds + 12288 + w * 1024);
        }
        __syncthreads();

        #pragma unroll
        for (int s = 0; s < 2; s++) {
            bf16x8 af[2], bfr[4];
            #pragma unroll
            for (int i = 0; i < 2; i++)
                af[i] = *(bf16x8*)&Alds[s * 2048 + (wm * 32 + i * 16 + lane15) * 32 + quad * 8];
            #pragma unroll
            for (int j = 0; j < 4; j++)
                bfr[j] = *(bf16x8*)&Blds[s * 4096 + (wn * 64 + j * 16 + lane15) * 32 + quad * 8];
            #pragma unroll
            for (int i = 0; i < 2; i++)
                #pragma unroll
                for (int j = 0; j < 4; j++)
                    acc[i][j] = __builtin_amdgcn_mfma_f32_16x16x32_bf16(af[i], bfr[j], acc[i][j], 0, 0, 0);
        }
    }

    const int bbu = m0 >> 11;          // batch index (block-uniform)
    const int t0  = m0 & (S_N - 1);    // global t of local row 0
    const int c0  = t0 >> 6;           // chunk index

    if (isq) {
        #pragma unroll
        for (int i = 0; i < 2; i++) {
            #pragma unroll
            for (int rg = 0; rg < 4; rg++) {
                int m = m0 + wm * 32 + i * 16 + quad * 4 + rg;
                int bb = m >> 11, t = m & (S_N - 1);
                #pragma unroll
                for (int j = 0; j < 4; j++) {
                    int n = bx * 128 + wn * 64 + j * 16 + lane15;   // 0..511
                    float val = acc[i][j][rg] + bqk[n];
                    val = (val > 0.f) ? (val + 1.f) : __expf(val);
                    qb[(((size_t)bb * H_N + (n >> 6)) * S_N + t) * DH + (n & 63)] = f2bf(val);
                }
            }
        }
        return;
    }

    // ---- kv epilogue: wn==0 half is k (elu+1), wn==1 half is v ----
    #pragma unroll
    for (int i = 0; i < 2; i++) {
        #pragma unroll
        for (int rg = 0; rg < 4; rg++) {
            int tl = wm * 32 + i * 16 + quad * 4 + rg;   // local row 0..63
            int t  = t0 + tl;
            #pragma unroll
            for (int j = 0; j < 4; j++) {
                int col = j * 16 + lane15;               // 0..63 within half
                if (wn == 0) {
                    float val = acc[i][j][rg] + bqk[512 + h * 64 + col];
                    val = (val > 0.f) ? (val + 1.f) : __expf(val);
                    unsigned short us = f2bf(val);
                    kb_[(((size_t)bbu * H_N + h) * S_N + t) * DH + col] = us;
                    ktT[col * 72 + tl] = us;
                } else {
                    float val = acc[i][j][rg] + bv[h * 64 + col];
                    vtT[col * 72 + tl] = f2bf(val);
                }
            }
        }
    }
    __syncthreads();

    // ---- coalesced copy vT -> vtb global [bh][d][t] ----
    {
        size_t vbase = (((size_t)bbu * H_N + h) * DH) * S_N + t0;
        #pragma unroll
        for (int it = 0; it < 2; it++) {
            int idx = it * 2048 + tid * 8;
            int d = idx >> 6, tt = idx & 63;
            *(bf16x8*)&vtb[vbase + (size_t)d * S_N + tt] = *(bf16x8*)&vtT[d * 72 + tt];
        }
    }

    // ---- St via MFMA; wave w owns d2 rows 16w..16w+15 ----
    {
        int blk = ((bbu * H_N + h) * NC) + c0;
        bf16x8 va[2];
        #pragma unroll
        for (int s = 0; s < 2; s++)
            va[s] = *(bf16x8*)&vtT[(w * 16 + lane15) * 72 + s * 32 + quad * 8];
        f32x4 sacc[4];
        #pragma unroll
        for (int j = 0; j < 4; j++) sacc[j] = (f32x4){0.f, 0.f, 0.f, 0.f};
        #pragma unroll
        for (int j = 0; j < 4; j++)
            #pragma unroll
            for (int s = 0; s < 2; s++) {
                bf16x8 kB = *(bf16x8*)&ktT[(j * 16 + lane15) * 72 + s * 32 + quad * 8];
                sacc[j] = __builtin_amdgcn_mfma_f32_16x16x32_bf16(va[s], kB, sacc[j], 0, 0, 0);
            }
        #pragma unroll
        for (int j = 0; j < 4; j++)
            #pragma unroll
            for (int rg = 0; rg < 4; rg++)
                Asum[(size_t)blk * 4096 + (w * 16 + quad * 4 + rg) * 64 + j * 16 + lane15] = sacc[j][rg];
    }

    // ---- z: threads 0..63, one d1 each ----
    if (tid < 64) {
        float z = 0.f;
        #pragma unroll
        for (int p = 0; p < 8; p++) {
            bf16x8 kk = *(bf16x8*)&ktT[tid * 72 + p * 8];
            #pragma unroll
            for (int e = 0; e < 8; e++) z += (float)kk[e];
        }
        zsum[(size_t)((bbu * H_N + h) * NC + c0) * 64 + tid] = z;
    }
}

// ---------------------------------------------------------------------------
// Kernel 2: per-chunk attention with INLINE state prefix (replaces the scan
// dispatch).  Block (bh,c) accumulates its own exclusive prefix of
// Asum[bh][0..c-1] (registers, 16 fp32/thread) into a padded LDS bf16 tile,
// and zsum prefix into LDS.  blockIdx swizzled so all chunks of one bh share
// bid%8 (XCD L2 locality for the redundant prefix reads).
// ---------------------------------------------------------------------------
__global__ __launch_bounds__(256) void attn_mfma(
    const unsigned short* __restrict__ qb, const unsigned short* __restrict__ kb_,
    const unsigned short* __restrict__ vtb, const float* __restrict__ Asum,
    const float* __restrict__ zsum, unsigned short* __restrict__ ctxb)
{
    __shared__ __align__(16) unsigned short P[64 * 72];
    __shared__ __align__(16) unsigned short Spre[64 * 72];   // [d2][d1] stride 72
    __shared__ float nupart[64][4];
    __shared__ float zc_s[64];

    const int bid = blockIdx.x;           // 0..511
    const int xcd = bid & 7, idx = bid >> 3;
    const int bh = xcd + 8 * (idx & 1);   // all 32 chunks of bh share bid%8
    const int c  = idx >> 1;
    const int b = bh >> 3, h = bh & 7;
    const int tid = threadIdx.x;
    const int w = tid >> 6, l = tid & 63;
    const int lane15 = l & 15, quad = l >> 4;

    const unsigned short* qc  = qb  + (size_t)bh * S_N * DH + c * CH * DH;  // [t][d]
    const unsigned short* kc  = kb_ + (size_t)bh * S_N * DH + c * CH * DH;  // [u][d]
    const unsigned short* vtc = vtb + (size_t)bh * DH * S_N + c * CH;       // [d2][t], stride S_N

    // ---- inline exclusive prefix: Asum[bh][0..c-1] -> Spre (bf16), z -> zc_s
    {
        const float* abase = Asum + (size_t)bh * NC * 4096;
        const int e = tid * 16;           // element 0..4095, 16 per thread
        float4 a0 = {0,0,0,0}, a1 = {0,0,0,0}, a2 = {0,0,0,0}, a3 = {0,0,0,0};
        for (int cc = 0; cc < c; cc++) {
            const float4* p = (const float4*)(abase + (size_t)cc * 4096 + e);
            float4 p0 = p[0], p1 = p[1], p2 = p[2], p3 = p[3];
            a0.x += p0.x; a0.y += p0.y; a0.z += p0.z; a0.w += p0.w;
            a1.x += p1.x; a1.y += p1.y; a1.z += p1.z; a1.w += p1.w;
            a2.x += p2.x; a2.y += p2.y; a2.z += p2.z; a2.w += p2.w;
            a3.x += p3.x; a3.y += p3.y; a3.z += p3.z; a3.w += p3.w;
        }
        const int d2 = e >> 6, d1 = e & 63;
        ushort4 u0 = {f2bf(a0.x), f2bf(a0.y), f2bf(a0.z), f2bf(a0.w)};
        ushort4 u1 = {f2bf(a1.x), f2bf(a1.y), f2bf(a1.z), f2bf(a1.w)};
        ushort4 u2 = {f2bf(a2.x), f2bf(a2.y), f2bf(a2.z), f2bf(a2.w)};
        ushort4 u3 = {f2bf(a3.x), f2bf(a3.y), f2bf(a3.z), f2bf(a3.w)};
        *(ushort4*)&Spre[d2 * 72 + d1]      = u0;
        *(ushort4*)&Spre[d2 * 72 + d1 + 4]  = u1;
        *(ushort4*)&Spre[d2 * 72 + d1 + 8]  = u2;
        *(ushort4*)&Spre[d2 * 72 + d1 + 12] = u3;

        if (tid < 64) {
            const float* zbase = zsum + (size_t)bh * NC * 64 + tid;
            float z = 0.f;
            for (int cc = 0; cc < c; cc++) z += zbase[cc * 64];
            zc_s[tid] = z;
        }
    }
    // (visibility of Spre/zc_s is covered by the __syncthreads after P store)

    bf16x8 af[2];
    #pragma unroll
    for (int s = 0; s < 2; s++)
        af[s] = *(const bf16x8*)&qc[(w * 16 + lane15) * DH + s * 32 + quad * 8];

    // scores S[t][u]
    f32x4 sacc[4];
    #pragma unroll
    for (int j = 0; j < 4; j++) sacc[j] = (f32x4){0.f, 0.f, 0.f, 0.f};
    #pragma unroll
    for (int j = 0; j < 4; j++)
        #pragma unroll
        for (int s = 0; s < 2; s++) {
            bf16x8 bk = *(const bf16x8*)&kc[(j * 16 + lane15) * DH + s * 32 + quad * 8];
            sacc[j] = __builtin_amdgcn_mfma_f32_16x16x32_bf16(af[s], bk, sacc[j], 0, 0, 0);
        }

    // causal mask + store P (bf16) to LDS
    const int r0 = w * 16 + quad * 4;
    #pragma unroll
    for (int j = 0; j < 4; j++) {
        int u = j * 16 + lane15;
        #pragma unroll
        for (int rg = 0; rg < 4; rg++) {
            int rr = r0 + rg;
            float v = (u <= rr) ? sacc[j][rg] : 0.f;
            P[rr * 72 + u] = f2bf(v);
        }
    }
    __syncthreads();

    // nu: thread (tl, part) sums P[tl][16*part..+15] + q.zprev strip
    const int tl = tid >> 2, part = tid & 3;
    float nup = 0.f;
    {
        bf16x8 p0 = *(const bf16x8*)&P[tl * 72 + part * 16];
        bf16x8 p1 = *(const bf16x8*)&P[tl * 72 + part * 16 + 8];
        bf16x8 q0 = *(const bf16x8*)&qc[tl * DH + part * 16];
        bf16x8 q1 = *(const bf16x8*)&qc[tl * DH + part * 16 + 8];
        #pragma unroll
        for (int i = 0; i < 8; i++) {
            nup += (float)p0[i] + (float)p1[i];
            nup += (float)q0[i] * zc_s[part * 16 + i];
            nup += (float)q1[i] * zc_s[part * 16 + 8 + i];
        }
    }
    nupart[tl][part] = nup;
    __syncthreads();

    // numerator: intra (P @ vt) + inter (q @ Spre), fused accumulator
    bf16x8 pa[2];
    #pragma unroll
    for (int s = 0; s < 2; s++)
        pa[s] = *(const bf16x8*)&P[(w * 16 + lane15) * 72 + s * 32 + quad * 8];

    f32x4 acc[4];
    #pragma unroll
    for (int j = 0; j < 4; j++) acc[j] = (f32x4){0.f, 0.f, 0.f, 0.f};
    #pragma unroll
    for (int j = 0; j < 4; j++)
        #pragma unroll
        for (int s = 0; s < 2; s++) {
            bf16x8 bv8 = *(const bf16x8*)&vtc[(size_t)(j * 16 + lane15) * S_N + s * 32 + quad * 8];
            acc[j] = __builtin_amdgcn_mfma_f32_16x16x32_bf16(pa[s], bv8, acc[j], 0, 0, 0);
            bf16x8 bs = *(const bf16x8*)&Spre[(j * 16 + lane15) * 72 + s * 32 + quad * 8];
            acc[j] = __builtin_amdgcn_mfma_f32_16x16x32_bf16(af[s], bs, acc[j], 0, 0, 0);
        }

    // epilogue: divide by nu, write ctx bf16 [b*S+t][DM]
    #pragma unroll
    for (int rg = 0; rg < 4; rg++) {
        int rr = r0 + rg;
        float nu = nupart[rr][0] + nupart[rr][1] + nupart[rr][2] + nupart[rr][3];
        float inv = 1.f / nu;
        size_t obase = ((size_t)b * S_N + c * CH + rr) * DM + h * DH;
        #pragma unroll
        for (int j = 0; j < 4; j++)
            ctxb[obase + j * 16 + lane15] = f2bf(acc[j][rg] * inv);
    }
}

// ---------------------------------------------------------------------------
// Kernel 3: output projection via bf16 MFMA.  64x64 tiles, BK=64, grid (8,64).
// ---------------------------------------------------------------------------
__global__ __launch_bounds__(256) void gemm_out_mfma(
    const unsigned short* __restrict__ ctxb,
    const unsigned short* __restrict__ Wob,
    const float* __restrict__ bo, float* __restrict__ out)
{
    __shared__ unsigned short Alds[2 * 64 * 32];
    __shared__ unsigned short Blds[2 * 64 * 32];
    const int tid = threadIdx.x;
    const int w = tid >> 6, l = tid & 63;
    const int wm = w >> 1, wn = w & 1;
    const int lane15 = l & 15, quad = l >> 4;
    const int n0 = blockIdx.x * 64;    // grid.x = 8
    const int m0 = blockIdx.y * 64;    // grid.y = 64

    const int srow = w * 16 + (l >> 2);
    const int skof = (l & 3) << 3;

    f32x4 acc[2][2];
    #pragma unroll
    for (int i = 0; i < 2; i++)
        #pragma unroll
        for (int j = 0; j < 2; j++) acc[i][j] = (f32x4){0.f, 0.f, 0.f, 0.f};

    for (int k0 = 0; k0 < DM; k0 += 64) {
        __syncthreads();
        gload16(&ctxb[(size_t)(m0 + srow) * DM + k0 + skof],      (char*)Alds + w * 1024);
        gload16(&ctxb[(size_t)(m0 + srow) * DM + k0 + 32 + skof], (char*)Alds + 4096 + w * 1024);
        gload16(&Wob[(size_t)(n0 + srow) * DM + k0 + skof],       (char*)Blds + w * 1024);
        gload16(&Wob[(size_t)(n0 + srow) * DM + k0 + 32 + skof],  (char*)Blds + 4096 + w * 1024);
        __syncthreads();

        #pragma unroll
        for (int s = 0; s < 2; s++) {
            bf16x8 af2[2], bfr[2];
            #pragma unroll
            for (int i = 0; i < 2; i++)
                af2[i] = *(bf16x8*)&Alds[s * 2048 + (wm * 32 + i * 16 + lane15) * 32 + quad * 8];
            #pragma unroll
            for (int j = 0; j < 2; j++)
                bfr[j] = *(bf16x8*)&Blds[s * 2048 + (wn * 32 + j * 16 + lane15) * 32 + quad * 8];
            #pragma unroll
            for (int i = 0; i < 2; i++)
                #pragma unroll
                for (int j = 0; j < 2; j++)
                    acc[i][j] = __builtin_amdgcn_mfma_f32_16x16x32_bf16(af2[i], bfr[j], acc[i][j], 0, 0, 0);
        }
    }

    #pragma unroll
    for (int i = 0; i < 2; i++) {
        #pragma unroll
        for (int rg = 0; rg < 4; rg++) {
            int m = m0 + wm * 32 + i * 16 + quad * 4 + rg;
            #pragma unroll
            for (int j = 0; j < 2; j++) {
                int n = n0 + wn * 32 + j * 16 + lane15;
                out[(size_t)m * DM + n] = acc[i][j][rg] + bo[n];
            }
        }
    }
}

// ---------------------------------------------------------------------------
extern "C" void kernel_launch(void* const* d_in, const int* in_sizes, int n_in,
                              void* d_out, int out_size, void* d_ws, size_t ws_size,
                              hipStream_t stream)
{
    const float* x   = (const float*)d_in[0];
    const float* Wqk = (const float*)d_in[1];
    const float* bqk = (const float*)d_in[2];
    const float* Wv  = (const float*)d_in[3];
    const float* bv  = (const float*)d_in[4];
    const float* Wo  = (const float*)d_in[5];
    const float* bo  = (const float*)d_in[6];
    float* out = (float*)d_out;

    const size_t NTOK = (size_t)B_N * S_N * DM;   // 2,097,152
    float* Asum = (float*)d_ws;                   // NTOK fp32
    float* zsum = Asum + NTOK;                    // 32768 fp32
    unsigned short* xb   = (unsigned short*)(zsum + 32768);
    unsigned short* Wqkb = xb   + NTOK;
    unsigned short* Wvb  = Wqkb + 524288;
    unsigned short* Wob  = Wvb  + 262144;
    unsigned short* qb   = Wob  + 262144;
    unsigned short* kb_  = qb   + NTOK;
    unsigned short* vtb  = kb_  + NTOK;
    unsigned short* ctxb = vtb  + NTOK;

    convert_bf16  <<<dim3(3072),   256, 0, stream>>>(x, Wqk, Wv, Wo, xb, Wqkb, Wvb, Wob);
    gemm_qkv_fused<<<dim3(12, 64), 256, 0, stream>>>(xb, Wqkb, Wvb, bqk, bv, qb, kb_, vtb, Asum, zsum);
    attn_mfma     <<<dim3(512),    256, 0, stream>>>(qb, kb_, vtb, Asum, zsum, ctxb);
    gemm_out_mfma <<<dim3(8, 64),  256, 0, stream>>>(ctxb, Wob, bo, out);
}